// Round 11
// baseline (1357.999 us; speedup 1.0000x reference)
//
#include <hip/hip_runtime.h>
#include <hip/hip_bf16.h>

// LSTMReg on MI355X — round 11: IN-REGISTER GATES (zbuf deleted).
// r10 audit: z LDS round-trip (32 b128 writes + 128 scalar b32 reads per
// CU-iter ~1100+ cyc) rivals MFMA issue (1242 cyc) -> LDS pipe co-bottleneck.
// New wave->tile map: wave owns one 16-row tile PER GATE ({w,w+4,w+8,w+12}),
// so its 4 accumulators hold z_i,z_f,z_g,z_o for the same 4 h of its
// (chain,parity) column. Parity pair = adjacent lanes -> one DPP quad_perm
// xor-1 + add per f32 completes z. Gates + c-state in registers (parity-
// redundant, bit-identical); p=0 lane writes h_hi, p=1 writes h_lo (1
// ds_write_b64 each). One barrier/iter. 8 waves x 64 blocks.
// Accumulation order per value identical to r9/r10 -> absmax 0.0 expected.

typedef short bf16x8 __attribute__((ext_vector_type(8)));
typedef short bf16x4 __attribute__((ext_vector_type(4)));
typedef float f32x4  __attribute__((ext_vector_type(4)));

#define MFMA16(A, B, C) __builtin_amdgcn_mfma_f32_16x16x32_bf16(A, B, C, 0, 0, 0)

constexpr int T_LEN = 1024;
constexpr int H     = 64;
constexpr int NCH   = 8;     // chains per block
constexpr int NTHR  = 512;   // 8 waves: wv 0-3 layer0, wv 4-7 layer1
constexpr int NBLK  = 64;    // 512 chains / 8

// x fragment buffer: [blk][t][kt(2)][lane(64)][8 shorts]  (same as r9/r10)
constexpr int    XT_SHORTS   = 2 * 64 * 8;                 // 1024 shorts per t
constexpr size_t XBLK_SHORTS = (size_t)T_LEN * XT_SHORTS;  // 2 MiB per block

__device__ __forceinline__ short f2bf(float f) {
  unsigned u = __builtin_bit_cast(unsigned, f);
  unsigned r = (u + 0x7fffu + ((u >> 16) & 1u)) >> 16;  // RNE
  return (short)r;
}
__device__ __forceinline__ float bf2f(short s) {
  unsigned u = ((unsigned)(unsigned short)s) << 16;
  return __builtin_bit_cast(float, u);
}
__device__ __forceinline__ float sigm_f(float x) {
  return __builtin_amdgcn_rcpf(1.0f + __expf(-x));
}
__device__ __forceinline__ float tanh_f(float x) {
  return 1.0f - 2.0f * __builtin_amdgcn_rcpf(1.0f + __expf(2.0f * x));
}
// neighbor-parity value: quad_perm [1,0,3,2] = xor lane bit0 (VALU pipe)
__device__ __forceinline__ float dpp_xor1(float v) {
  int o = __builtin_amdgcn_mov_dpp(__builtin_bit_cast(int, v), 0xB1, 0xF, 0xF, true);
  return __builtin_bit_cast(float, o);
}

// ---- pre-pass: pack x into B-fragment packets, col parity = hi/lo part ----
__global__ __launch_bounds__(256, 4) void xconv(const float* __restrict__ x,
                                                short* __restrict__ xf) {
  const int gid = blockIdx.x * 256 + threadIdx.x;
  const int l   = gid & 63;
  const int t   = (gid >> 6) & (T_LEN - 1);
  const int blk = gid >> 16;
  const int part = l & 1, ch = (l >> 1) & 7, f0 = (l >> 4) * 8;
  const float* src = x + ((size_t)(blk * NCH + ch) * T_LEN + t) * H + f0;
  float4 v0 = *reinterpret_cast<const float4*>(src);
  float4 v1 = *reinterpret_cast<const float4*>(src + 4);
  float4 v2 = *reinterpret_cast<const float4*>(src + 32);
  float4 v3 = *reinterpret_cast<const float4*>(src + 36);
  float a[8]  = {v0.x, v0.y, v0.z, v0.w, v1.x, v1.y, v1.z, v1.w};
  float c8[8] = {v2.x, v2.y, v2.z, v2.w, v3.x, v3.y, v3.z, v3.w};
  bf16x8 p0, p1;
#pragma unroll
  for (int e = 0; e < 8; ++e) {
    short h0 = f2bf(a[e]);
    short h1 = f2bf(c8[e]);
    if (part == 0) { p0[e] = h0; p1[e] = h1; }
    else { p0[e] = f2bf(a[e] - bf2f(h0)); p1[e] = f2bf(c8[e] - bf2f(h1)); }
  }
  short* dst = xf + (size_t)blk * XBLK_SHORTS + (size_t)t * XT_SHORTS + l * 8;
  *reinterpret_cast<bf16x8*>(dst)       = p0;  // kt0 (feats 0-31)
  *reinterpret_cast<bf16x8*>(dst + 512) = p1;  // kt1 (feats 32-63)
}

__global__ __launch_bounds__(NTHR, 2) void lstm_fused(
    const short* __restrict__ xf,
    const float* __restrict__ w_ih0, const float* __restrict__ w_hh0,
    const float* __restrict__ b_ih0, const float* __restrict__ b_hh0,
    const float* __restrict__ w_ih1, const float* __restrict__ w_hh1,
    const float* __restrict__ b_ih1, const float* __restrict__ b_hh1,
    const float* __restrict__ fc_w, const float* __restrict__ fc_b,
    float* __restrict__ out) {
  const int tid = threadIdx.x;
  const int wv  = tid >> 6;
  const int L   = wv >> 2;   // 0: layer0 waves (wv 0-3), 1: layer1 (wv 4-7)
  const int w   = wv & 3;    // wave's feat block: gate g rows 64g+16w..+16
  const int l   = tid & 63;
  const int col = l & 15;    // MFMA column = 2*chain + parity
  const int lq  = l >> 4;
  const int p   = l & 1;     // parity: 0 = hi, 1 = lo
  const int blk = blockIdx.x;

  // h buffers, fragment-linear + XOR swizzle (verified r9/r10)
  __shared__ __align__(16) short hb[2][2][2][520];  // [layer][buf][half][520]
  __shared__ float fcw_s[H];
  __shared__ float hfin[NCH][H];

  for (int i = tid; i < 2 * 2 * 2 * 520; i += NTHR) ((short*)hb)[i] = 0;
  if (tid < H) fcw_s[tid] = fc_w[tid];

  // ---- weights: gate g tile = rows 64g + 16w + col; k0 = 32kt + 8lq ----
  const float* wih = L ? w_ih1 : w_ih0;
  const float* whh = L ? w_hh1 : w_hh0;
  const float* bih = L ? b_ih1 : b_ih0;
  const float* bhh = L ? b_hh1 : b_hh0;
  bf16x8 whi[4][4], wlo[4][4];  // [gate][kt] = 128 VGPR
  f32x4  biasf[4];
#pragma unroll
  for (int g = 0; g < 4; ++g) {
#pragma unroll
    for (int kt = 0; kt < 4; ++kt) {
      const int row = 64 * g + 16 * w + col;
      const int k0  = 32 * kt + 8 * lq;
      const float* src = (k0 < 64) ? &wih[row * 64 + k0] : &whh[row * 64 + (k0 - 64)];
      float4 v0 = *reinterpret_cast<const float4*>(src);
      float4 v1 = *reinterpret_cast<const float4*>(src + 4);
      float vv[8] = {v0.x, v0.y, v0.z, v0.w, v1.x, v1.y, v1.z, v1.w};
      bf16x8 hi8, lo8;
#pragma unroll
      for (int e = 0; e < 8; ++e) {
        short hh = f2bf(vv[e]);
        hi8[e] = hh;
        lo8[e] = f2bf(vv[e] - bf2f(hh));
      }
      whi[g][kt] = hi8;
      wlo[g][kt] = lo8;
    }
#pragma unroll
    for (int r = 0; r < 4; ++r) {
      int row = 64 * g + 16 * w + 4 * lq + r;
      biasf[g][r] = bih[row] + bhh[row];
    }
  }

  __syncthreads();  // hb zeros visible

  // reader LDS offset (shorts): swizzled slot * 8 (verified r9)
  const int rdoff = ((l & 48) | ((l & 15) ^ ((l >> 4) << 1))) * 8;
  // writer: this lane produces h[feat0..feat0+3] for chain col>>1, part p
  const int feat0 = 16 * w + 4 * lq;
  const int q0    = (feat0 >> 3) & 3;
  const int woff  = (feat0 >> 5) * 520 + ((q0 << 4) | (col ^ (q0 << 1))) * 8 + (feat0 & 7);

  // x prefetch (L0 waves)
  const short* xfl = xf + (size_t)blk * XBLK_SHORTS + l * 8;
  bf16x8 xb0, xb1, xbn0, xbn1;
  if (L == 0) {
    xb0 = *reinterpret_cast<const bf16x8*>(xfl);
    xb1 = *reinterpret_cast<const bf16x8*>(xfl + 512);
  }

  f32x4 cst = {0.f, 0.f, 0.f, 0.f};
  const f32x4 zf4 = {0.f, 0.f, 0.f, 0.f};

  // 8 MFMAs per k-tile (4 gates x hi/lo), round-robin gates for ILP.
  // Per-acc order: whi[g][kt]B, wlo[g][kt]B, kt ascending == r9/r10 order.
#define KT8(kt, B_)                                                   \
  a0 = MFMA16(whi[0][kt], B_, a0); a1 = MFMA16(whi[1][kt], B_, a1);   \
  a2 = MFMA16(whi[2][kt], B_, a2); a3 = MFMA16(whi[3][kt], B_, a3);   \
  a0 = MFMA16(wlo[0][kt], B_, a0); a1 = MFMA16(wlo[1][kt], B_, a1);   \
  a2 = MFMA16(wlo[2][kt], B_, a2); a3 = MFMA16(wlo[3][kt], B_, a3);

  for (int t = 0; t <= T_LEN; ++t) {
    const int cur = t & 1, nxt = cur ^ 1;

    if (L == 0 && t + 1 < T_LEN) {  // issue x[t+1] loads early
      const short* px = xfl + (size_t)(t + 1) * XT_SHORTS;
      xbn0 = *reinterpret_cast<const bf16x8*>(px);
      xbn1 = *reinterpret_cast<const bf16x8*>(px + 512);
    }

    const bool act = (L == 0) ? (t < T_LEN) : (t >= 1);
    if (act) {
      f32x4 a0 = zf4, a1 = zf4, a2 = zf4, a3 = zf4;
      const short* h0c = &hb[0][cur][0][0];
      if (L == 0) {
        bf16x8 B2 = *reinterpret_cast<const bf16x8*>(h0c + rdoff);
        bf16x8 B3 = *reinterpret_cast<const bf16x8*>(h0c + 520 + rdoff);
        KT8(0, xb0) KT8(1, xb1) KT8(2, B2) KT8(3, B3)
      } else {
        const short* h1c = &hb[1][cur][0][0];
        bf16x8 B0 = *reinterpret_cast<const bf16x8*>(h0c + rdoff);
        bf16x8 B1 = *reinterpret_cast<const bf16x8*>(h0c + 520 + rdoff);
        bf16x8 B2 = *reinterpret_cast<const bf16x8*>(h1c + rdoff);
        bf16x8 B3 = *reinterpret_cast<const bf16x8*>(h1c + 520 + rdoff);
        KT8(0, B0) KT8(1, B1) KT8(2, B2) KT8(3, B3)
      }

      // parity-pair sum (DPP xor-1) + bias -> full z, then gates in-register
      f32x4 hv;
#pragma unroll
      for (int r = 0; r < 4; ++r) {
        float z0 = (a0[r] + dpp_xor1(a0[r])) + biasf[0][r];
        float z1 = (a1[r] + dpp_xor1(a1[r])) + biasf[1][r];
        float z2 = (a2[r] + dpp_xor1(a2[r])) + biasf[2][r];
        float z3 = (a3[r] + dpp_xor1(a3[r])) + biasf[3][r];
        float ig = sigm_f(z0), fg = sigm_f(z1);
        float gg = tanh_f(z2), og = sigm_f(z3);
        cst[r] = fg * cst[r] + ig * gg;
        hv[r]  = og * tanh_f(cst[r]);
      }

      if (L == 1 && t == T_LEN) {
        if (p == 0) *reinterpret_cast<f32x4*>(&hfin[col >> 1][feat0]) = hv;
      } else {
        bf16x4 o4;
#pragma unroll
        for (int r = 0; r < 4; ++r) {
          short hi = f2bf(hv[r]);
          o4[r] = p ? f2bf(hv[r] - bf2f(hi)) : hi;
        }
        short* base = &hb[L][nxt][0][0];
        *reinterpret_cast<bf16x4*>(base + woff) = o4;
      }
    }

    __syncthreads();  // h[nxt] ready
    if (L == 0) { xb0 = xbn0; xb1 = xbn1; }
  }
#undef KT8

  // ---- FC epilogue ----
  if (tid < NCH) {
    float acc = fc_b[0];
#pragma unroll
    for (int h = 0; h < H; ++h) acc += fcw_s[h] * hfin[tid][h];
    out[blk * NCH + tid] = acc;
  }
}

extern "C" void kernel_launch(void* const* d_in, const int* in_sizes, int n_in,
                              void* d_out, int out_size, void* d_ws, size_t ws_size,
                              hipStream_t stream) {
  const float* x     = (const float*)d_in[0];
  const float* w_ih0 = (const float*)d_in[1];
  const float* w_hh0 = (const float*)d_in[2];
  const float* b_ih0 = (const float*)d_in[3];
  const float* b_hh0 = (const float*)d_in[4];
  const float* w_ih1 = (const float*)d_in[5];
  const float* w_hh1 = (const float*)d_in[6];
  const float* b_ih1 = (const float*)d_in[7];
  const float* b_hh1 = (const float*)d_in[8];
  const float* fc_w  = (const float*)d_in[9];
  const float* fc_b  = (const float*)d_in[10];
  float* out = (float*)d_out;

  short* xfrag = (short*)d_ws;  // 128 MiB exactly

  xconv<<<dim3(16384), dim3(256), 0, stream>>>(x, xfrag);
  lstm_fused<<<dim3(NBLK), dim3(NTHR), 0, stream>>>(
      xfrag, w_ih0, w_hh0, b_ih0, b_hh0, w_ih1, w_hh1, b_ih1, b_hh1,
      fc_w, fc_b, out);
}